// Round 5
// baseline (233.042 us; speedup 1.0000x reference)
//
#include <hip/hip_runtime.h>

// ColorHistogramLoss: B=32, C=3, H=W=512, BINS=64.
// v4: private per-thread u32 columns + ds_add_u32 (return-less LDS atomic).
// One LDS instruction per element, fire-and-forget: no read-modify-write chain,
// no waitcnts in the hot loop (v3c was latency-serialized on ds_read_u16 ->
// add -> ds_write_b16 with compiler-enforced ordering: 74us at 15% VALU).
// Private columns: hist[row][tid], bank = tid&31 -> exactly 2 lanes/bank (free),
// data-independent. Signed diff: input adds 1, target adds 0xFFFFFFFF (mod 2^32).

#define BINS 64
#define PLANES 96          // B*C
#define PLANE_F4 65536     // 512*512/4
#define SEGS 32            // segments per plane
#define SEG_F4 2048        // PLANE_F4/SEGS
#define TPB 256
#define F4T 8              // float4 per thread per tensor
#define NROWS 65           // 64 bins + trash row for v < -1
#define LDS_U32 (NROWS * 256)            // 16640 words = 66560 B -> 2 blocks/CU

// bin = trunc((v+1)*31.5); v>=1 -> 63 (clamp); v<-1 -> trash row 64.
// Same arithmetic as the absmax==0-verified v1/v3 formula.
__device__ __forceinline__ void bump(unsigned int* __restrict__ col, float v,
                                     unsigned int delta) {
    int bin = (int)((v + 1.0f) * 31.5f);
    bin = bin > 63 ? 63 : bin;
    int row = (v < -1.0f) ? 64 : bin;
    atomicAdd(&col[row * 256], delta);   // ds_add_u32, no return -> no chain
}

__global__ __launch_bounds__(TPB) void hist_diff_kernel(
        const float4* __restrict__ in4, const float4* __restrict__ tg4,
        int* __restrict__ gdiff) {
    __shared__ __align__(16) unsigned int hist[NROWS][256];

    const int tid  = threadIdx.x;
    const int lane = tid & 63;
    const int wid  = tid >> 6;

    // zero LDS with b128 stores: 4160 uint4
    {
        uint4* p = (uint4*)&hist[0][0];
        const uint4 z = make_uint4(0, 0, 0, 0);
#pragma unroll
        for (int i = 0; i < 17; ++i) {
            int idx = tid + i * TPB;
            if (idx < LDS_U32 / 4) p[idx] = z;
        }
    }
    __syncthreads();

    const int plane = blockIdx.x >> 5;           // /SEGS
    const int seg   = blockIdx.x & (SEGS - 1);
    const long base = (long)plane * PLANE_F4 + (long)seg * SEG_F4 + tid;

    // stage all 16 float4 loads up front; vmcnt pipelining hides HBM/L3 latency
    float4 a[F4T], b[F4T];
#pragma unroll
    for (int k = 0; k < F4T; ++k) a[k] = in4[base + k * TPB];
#pragma unroll
    for (int k = 0; k < F4T; ++k) b[k] = tg4[base + k * TPB];

    unsigned int* col = &hist[0][tid];
#pragma unroll
    for (int k = 0; k < F4T; ++k) {
        bump(col, a[k].x, 1u); bump(col, a[k].y, 1u);
        bump(col, a[k].z, 1u); bump(col, a[k].w, 1u);
    }
#pragma unroll
    for (int k = 0; k < F4T; ++k) {
        bump(col, b[k].x, 0xFFFFFFFFu); bump(col, b[k].y, 0xFFFFFFFFu);
        bump(col, b[k].z, 0xFFFFFFFFu); bump(col, b[k].w, 0xFFFFFFFFu);
    }
    __syncthreads();

    // merge: wave w sums columns [w*64, w*64+64) of row 'lane' (bin):
    // 16x ds_read_b128, diagonal (it+lane)&15 to spread banks. |col val| <= 32.
    {
        const uint4* rowp = (const uint4*)&hist[lane][wid * 64];
        int s = 0;
#pragma unroll
        for (int it = 0; it < 16; ++it) {
            int j = (it + lane) & 15;
            uint4 w4 = rowp[j];
            s += (int)w4.x + (int)w4.y + (int)w4.z + (int)w4.w;
        }
        if (s != 0) atomicAdd(&gdiff[plane * BINS + lane], s);  // 64 distinct addrs
    }
}

__global__ __launch_bounds__(TPB) void reduce_abs_kernel(
        const int* __restrict__ gdiff, float* __restrict__ out) {
    int s = 0;
    for (int i = threadIdx.x; i < PLANES * BINS; i += TPB) {
        int v = gdiff[i];
        s += (v < 0) ? -v : v;
    }
    // wave64 butterfly
#pragma unroll
    for (int off = 32; off > 0; off >>= 1) s += __shfl_down(s, off, 64);
    __shared__ int ws[TPB / 64];
    const int wid  = threadIdx.x >> 6;
    const int lane = threadIdx.x & 63;
    if (lane == 0) ws[wid] = s;
    __syncthreads();
    if (threadIdx.x == 0) {
        int total = 0;
#pragma unroll
        for (int w = 0; w < TPB / 64; ++w) total += ws[w];
        // loss = total / N / (B*C*BINS); |total| < 2^24 so exact in fp32
        out[0] = (float)total * (1.0f / (262144.0f * 6144.0f));
    }
}

extern "C" void kernel_launch(void* const* d_in, const int* in_sizes, int n_in,
                              void* d_out, int out_size, void* d_ws, size_t ws_size,
                              hipStream_t stream) {
    const float4* inp = (const float4*)d_in[0];
    const float4* tgt = (const float4*)d_in[1];
    int* gdiff = (int*)d_ws;   // 96*64 signed counts, 24 KiB

    hipMemsetAsync(gdiff, 0, PLANES * BINS * sizeof(int), stream);
    hist_diff_kernel<<<PLANES * SEGS, TPB, 0, stream>>>(inp, tgt, gdiff);
    reduce_abs_kernel<<<1, TPB, 0, stream>>>(gdiff, (float*)d_out);
}

// Round 7
// 215.362 us; speedup vs baseline: 1.0821x; 1.0821x over previous
//
#include <hip/hip_runtime.h>

// ColorHistogramLoss: B=32, C=3, H=W=512, BINS=64.
// v5: packed-pair u32 private columns, non-atomic b32 RMW.
// Evidence: v4 showed ds_add_u32 ~72 cyc/wave-instr (atomic unit ~1 lane/cyc);
// v3c showed sub-word ds_read_u16/ds_write_b16 ~29 cyc/instr. Full-width b32
// read+add+write at 2 lanes/bank runs at ~6 cyc (m134/m136). To keep u32
// counters in 33.8KB (4 blocks/CU), pack bins 2r/2r+1 into one u32 as two
// biased u16 fields (bias 128; per-thread |net|<=32 so fields stay in [96,160]
// -> no cross-field borrow; deltas +-1 / +-0x10000 as plain u32 adds).
// Bank = tid%32, data-independent: 2 lanes/bank different-address = free.

#define BINS 64
#define PLANES 96          // B*C
#define PLANE_F4 65536     // 512*512/4
#define SEGS 32            // segments per plane
#define SEG_F4 2048        // PLANE_F4/SEGS
#define TPB 256
#define F4T 8              // float4 per thread per tensor
#define PROWS 33           // 32 packed bin-pair rows + 1 trash row (v < -1)
#define LDS_W (PROWS * 256)   // 8448 u32 = 33792 B -> 4 blocks/CU
#define BIAS 128
#define INIT_W 0x00800080u    // both fields at BIAS

// bin = trunc((v+1)*31.5) (== floor for v >= -1); v>=1 clamps to 63; v<-1 -> trash
// row 32. Same binning arithmetic as the absmax==0-verified v1/v3 kernels.
__device__ __forceinline__ void bump(unsigned int* __restrict__ col, float v,
                                     bool neg) {
    int bin = (int)((v + 1.0f) * 31.5f);
    bin = bin > 63 ? 63 : bin;
    int row = (v < -1.0f) ? 32 : (bin >> 1);
    unsigned int d = 1u << ((bin & 1) << 4);      // 1 or 0x10000
    unsigned int* p = &col[row * 256];
    *p += neg ? (0u - d) : d;                     // b32 read + add + write
}

__global__ __launch_bounds__(TPB) void hist_diff_kernel(
        const float4* __restrict__ in4, const float4* __restrict__ tg4,
        int* __restrict__ gdiff) {
    __shared__ __align__(16) unsigned int hist[PROWS][256];   // 33792 B

    const int tid  = threadIdx.x;
    const int lane = tid & 63;
    const int wid  = tid >> 6;

    // init all packed fields to BIAS with b128 stores (2112 uint4)
    {
        uint4* p = (uint4*)&hist[0][0];
        const uint4 z = make_uint4(INIT_W, INIT_W, INIT_W, INIT_W);
#pragma unroll
        for (int i = 0; i < 9; ++i) {
            int idx = tid + i * TPB;
            if (idx < LDS_W / 4) p[idx] = z;
        }
    }
    __syncthreads();

    const int plane = blockIdx.x >> 5;           // /SEGS
    const int seg   = blockIdx.x & (SEGS - 1);
    const long base = (long)plane * PLANE_F4 + (long)seg * SEG_F4 + tid;

    // stage all 16 float4 loads up front; vmcnt pipelining hides HBM/L3 latency
    float4 a[F4T], b[F4T];
#pragma unroll
    for (int k = 0; k < F4T; ++k) a[k] = in4[base + k * TPB];
#pragma unroll
    for (int k = 0; k < F4T; ++k) b[k] = tg4[base + k * TPB];

    unsigned int* col = &hist[0][tid];
#pragma unroll
    for (int k = 0; k < F4T; ++k) {
        bump(col, a[k].x, false); bump(col, a[k].y, false);
        bump(col, a[k].z, false); bump(col, a[k].w, false);
    }
#pragma unroll
    for (int k = 0; k < F4T; ++k) {
        bump(col, b[k].x, true); bump(col, b[k].y, true);
        bump(col, b[k].z, true); bump(col, b[k].w, true);
    }
    __syncthreads();

    // merge: lane L handles bin L = 2*(L>>1) + (L&1): row r = L>>1, field L&1.
    // Wave wid sums its 64-column slice [wid*64, wid*64+64) = 16 uint4.
    // Lanes 2k/2k+1 read identical addresses (broadcast, free); diagonal
    // j=(it+r)&15 spreads the 32 distinct rows across bank groups (2-way, free).
    // Packed u32 adds are exact: per-field sum <= 64*160 = 10240 < 65536.
    {
        const int r = lane >> 1;
        const uint4* rowp = (const uint4*)&hist[r][wid * 64];
        unsigned int acc = 0;
#pragma unroll
        for (int it = 0; it < 16; ++it) {
            int j = (it + r) & 15;
            uint4 w4 = rowp[j];
            acc += w4.x + w4.y + w4.z + w4.w;
        }
        int s = (int)((acc >> ((lane & 1) << 4)) & 0xFFFFu) - 64 * BIAS;
        if (s != 0) atomicAdd(&gdiff[plane * BINS + lane], s);
    }
}

__global__ __launch_bounds__(TPB) void reduce_abs_kernel(
        const int* __restrict__ gdiff, float* __restrict__ out) {
    int s = 0;
    for (int i = threadIdx.x; i < PLANES * BINS; i += TPB) {
        int v = gdiff[i];
        s += (v < 0) ? -v : v;
    }
    // wave64 butterfly
#pragma unroll
    for (int off = 32; off > 0; off >>= 1) s += __shfl_down(s, off, 64);
    __shared__ int ws[TPB / 64];
    const int wid  = threadIdx.x >> 6;
    const int lane = threadIdx.x & 63;
    if (lane == 0) ws[wid] = s;
    __syncthreads();
    if (threadIdx.x == 0) {
        int total = 0;
#pragma unroll
        for (int w = 0; w < TPB / 64; ++w) total += ws[w];
        // loss = total / N / (B*C*BINS); |total| < 2^24 so exact in fp32
        out[0] = (float)total * (1.0f / (262144.0f * 6144.0f));
    }
}

extern "C" void kernel_launch(void* const* d_in, const int* in_sizes, int n_in,
                              void* d_out, int out_size, void* d_ws, size_t ws_size,
                              hipStream_t stream) {
    const float4* inp = (const float4*)d_in[0];
    const float4* tgt = (const float4*)d_in[1];
    int* gdiff = (int*)d_ws;   // 96*64 signed counts, 24 KiB

    hipMemsetAsync(gdiff, 0, PLANES * BINS * sizeof(int), stream);
    hist_diff_kernel<<<PLANES * SEGS, TPB, 0, stream>>>(inp, tgt, gdiff);
    reduce_abs_kernel<<<1, TPB, 0, stream>>>(gdiff, (float*)d_out);
}

// Round 8
// 214.948 us; speedup vs baseline: 1.0842x; 1.0019x over previous
//
#include <hip/hip_runtime.h>

// ColorHistogramLoss: B=32, C=3, H=W=512, BINS=64.
// v6: v5 (packed-pair u32 private columns) + 4-wide batched RMW.
// Evidence chain: v5 measured 80us with NO pipe busy (VALU 17%, HBM 16%,
// conflicts 0) -> bound by the serial per-element ds_read->add->ds_write
// dependency chain (compiler can't reorder around data-dependent LDS writes).
// Fix: per float4, issue 4 ds_reads back-to-back, resolve same-row duplicates
// in registers (merge deltas forward; redirect duplicate WRITES to trash row
// so stale reads never clobber merged writes), then 4 ds_writes. DS ops are
// in-order per wave -> cross-batch RAW is safe with no extra waits.
// Chain stalls per thread: 32 -> 8.

#define BINS 64
#define PLANES 96          // B*C
#define PLANE_F4 65536     // 512*512/4
#define SEGS 32            // segments per plane
#define SEG_F4 2048        // PLANE_F4/SEGS
#define TPB 256
#define F4T 8              // float4 per thread per tensor
#define PROWS 33           // 32 packed bin-pair rows + 1 trash row
#define TRASH 32
#define LDS_W (PROWS * 256)   // 8448 u32 = 33792 B -> 4 blocks/CU
#define BIAS 128
#define INIT_W 0x00800080u    // both fields at BIAS

// bin = trunc((v+1)*31.5) (== floor for v >= -1); v>=1 clamps to 63; v<-1 -> trash
// row. Same binning arithmetic as the absmax==0-verified v1/v3/v5 kernels.
__device__ __forceinline__ void binrd(float v, int& row, unsigned& d) {
    int bin = (int)((v + 1.0f) * 31.5f);
    bin = bin > 63 ? 63 : bin;
    row = (v < -1.0f) ? TRASH : (bin >> 1);
    d = 1u << ((bin & 1) << 4);       // 1 or 0x10000 (field-coded delta)
}

__device__ __forceinline__ void bump4(unsigned int* __restrict__ col, float4 q,
                                      bool neg) {
    int r0, r1, r2, r3; unsigned d0, d1, d2, d3;
    binrd(q.x, r0, d0); binrd(q.y, r1, d1);
    binrd(q.z, r2, d2); binrd(q.w, r3, d3);
    if (neg) { d0 = 0u - d0; d1 = 0u - d1; d2 = 0u - d2; d3 = 0u - d3; }

    unsigned int* p0 = &col[r0 * 256];
    unsigned int* p1 = &col[r1 * 256];
    unsigned int* p2 = &col[r2 * 256];
    unsigned int* p3 = &col[r3 * 256];
    // 4 independent ds_reads issue back-to-back (in-order DS pipe)
    unsigned u0 = *p0, u1 = *p1, u2 = *p2, u3 = *p3;

    // same-row duplicates: merge deltas forward into first occurrence
    bool e01 = (r1 == r0);
    bool e02 = (r2 == r0), e12 = (r2 == r1);
    bool e03 = (r3 == r0), e13 = (r3 == r1), e23 = (r3 == r2);
    unsigned a0 = d0 + (e01 ? d1 : 0u) + (e02 ? d2 : 0u) + (e03 ? d3 : 0u);
    unsigned a1 = d1 + (e12 ? d2 : 0u) + (e13 ? d3 : 0u);
    unsigned a2 = d2 + (e23 ? d3 : 0u);
    // duplicate writes go to the trash row (their delta already merged upstream;
    // field sums per batch <= 4 so packed adds never carry across fields)
    unsigned int* t = &col[TRASH * 256];
    unsigned int* q1 = e01 ? t : p1;
    unsigned int* q2 = (e02 | e12) ? t : p2;
    unsigned int* q3 = (e03 | e13 | e23) ? t : p3;
    *p0 = u0 + a0;
    *q1 = u1 + a1;
    *q2 = u2 + a2;
    *q3 = u3 + d3;
}

__global__ __launch_bounds__(TPB) void hist_diff_kernel(
        const float4* __restrict__ in4, const float4* __restrict__ tg4,
        int* __restrict__ gdiff) {
    __shared__ __align__(16) unsigned int hist[PROWS][256];   // 33792 B

    const int tid  = threadIdx.x;
    const int lane = tid & 63;
    const int wid  = tid >> 6;

    // init all packed fields to BIAS with b128 stores (2112 uint4)
    {
        uint4* p = (uint4*)&hist[0][0];
        const uint4 z = make_uint4(INIT_W, INIT_W, INIT_W, INIT_W);
#pragma unroll
        for (int i = 0; i < 9; ++i) {
            int idx = tid + i * TPB;
            if (idx < LDS_W / 4) p[idx] = z;
        }
    }
    __syncthreads();

    const int plane = blockIdx.x >> 5;           // /SEGS
    const int seg   = blockIdx.x & (SEGS - 1);
    const long base = (long)plane * PLANE_F4 + (long)seg * SEG_F4 + tid;

    // stage all 16 float4 loads up front; vmcnt pipelining hides HBM/L3 latency
    float4 a[F4T], b[F4T];
#pragma unroll
    for (int k = 0; k < F4T; ++k) a[k] = in4[base + k * TPB];
#pragma unroll
    for (int k = 0; k < F4T; ++k) b[k] = tg4[base + k * TPB];

    unsigned int* col = &hist[0][tid];
#pragma unroll
    for (int k = 0; k < F4T; ++k) bump4(col, a[k], false);
#pragma unroll
    for (int k = 0; k < F4T; ++k) bump4(col, b[k], true);
    __syncthreads();

    // merge: lane L handles bin L: row r = L>>1, field L&1.
    // Wave wid sums its 64-column slice [wid*64, wid*64+64) = 16 uint4.
    // Lanes 2k/2k+1 read identical addresses (broadcast, free); diagonal
    // j=(it+r)&15 spreads rows (2-way max = free).
    // Packed u32 adds exact: per-field sum <= 64*160 = 10240 < 65536.
    {
        const int r = lane >> 1;
        const uint4* rowp = (const uint4*)&hist[r][wid * 64];
        unsigned int acc = 0;
#pragma unroll
        for (int it = 0; it < 16; ++it) {
            int j = (it + r) & 15;
            uint4 w4 = rowp[j];
            acc += w4.x + w4.y + w4.z + w4.w;
        }
        int s = (int)((acc >> ((lane & 1) << 4)) & 0xFFFFu) - 64 * BIAS;
        if (s != 0) atomicAdd(&gdiff[plane * BINS + lane], s);
    }
}

__global__ __launch_bounds__(TPB) void reduce_abs_kernel(
        const int* __restrict__ gdiff, float* __restrict__ out) {
    int s = 0;
    for (int i = threadIdx.x; i < PLANES * BINS; i += TPB) {
        int v = gdiff[i];
        s += (v < 0) ? -v : v;
    }
    // wave64 butterfly
#pragma unroll
    for (int off = 32; off > 0; off >>= 1) s += __shfl_down(s, off, 64);
    __shared__ int ws[TPB / 64];
    const int wid  = threadIdx.x >> 6;
    const int lane = threadIdx.x & 63;
    if (lane == 0) ws[wid] = s;
    __syncthreads();
    if (threadIdx.x == 0) {
        int total = 0;
#pragma unroll
        for (int w = 0; w < TPB / 64; ++w) total += ws[w];
        // loss = total / N / (B*C*BINS); |total| < 2^24 so exact in fp32
        out[0] = (float)total * (1.0f / (262144.0f * 6144.0f));
    }
}

extern "C" void kernel_launch(void* const* d_in, const int* in_sizes, int n_in,
                              void* d_out, int out_size, void* d_ws, size_t ws_size,
                              hipStream_t stream) {
    const float4* inp = (const float4*)d_in[0];
    const float4* tgt = (const float4*)d_in[1];
    int* gdiff = (int*)d_ws;   // 96*64 signed counts, 24 KiB

    hipMemsetAsync(gdiff, 0, PLANES * BINS * sizeof(int), stream);
    hist_diff_kernel<<<PLANES * SEGS, TPB, 0, stream>>>(inp, tgt, gdiff);
    reduce_abs_kernel<<<1, TPB, 0, stream>>>(gdiff, (float*)d_out);
}